// Round 7
// baseline (545.651 us; speedup 1.0000x reference)
//
#include <hip/hip_runtime.h>

#define BATCH 4
#define SEQ 2048
#define HEADS 16
#define DHEAD 64
#define HID 1024
#define MROWS (BATCH * SEQ)   // 8192
#define QSCALE 0.1803368801111092f   // 0.125 * log2(e): exp2 domain

typedef unsigned short u16;
typedef unsigned int u32;
typedef __attribute__((ext_vector_type(4))) float f32x4;
typedef __attribute__((ext_vector_type(8))) short bf16x8;

#define MFMA16(a, b, c) __builtin_amdgcn_mfma_f32_16x16x32_bf16((a), (b), (c), 0, 0, 0)
#define EXP2F(x) __builtin_amdgcn_exp2f(x)

__device__ __forceinline__ float bflo(u32 w) { union { u32 i; float f; } x; x.i = w << 16; return x.f; }
__device__ __forceinline__ float bfhi(u32 w) { union { u32 i; float f; } x; x.i = w & 0xffff0000u; return x.f; }
// f32 -> bf16 round-to-nearest-even (finite inputs)
__device__ __forceinline__ u16 f2bf(float f) {
  union { float f; u32 i; } x; x.f = f;
  u32 r = x.i + 0x7fffu + ((x.i >> 16) & 1u);
  return (u16)(r >> 16);
}
__device__ __forceinline__ u32 fbits(float f) { union { float f; u32 i; } x; x.f = f; return x.i; }
__device__ __forceinline__ float asf(u32 i) { union { u32 i; float f; } x; x.i = i; return x.f; }

// async global->LDS, 16 B/lane.  LDS dest must be wave-uniform base + lane*16.
__device__ __forceinline__ void lds16(const u16* g, u16* s) {
  __builtin_amdgcn_global_load_lds(
      (const __attribute__((address_space(1))) void*)g,
      (__attribute__((address_space(3))) void*)s, 16, 0, 0);
}

// VALU staging: 8 fp32 -> 8 bf16
__device__ __forceinline__ void stage8f(const float* __restrict__ g, u16* s) {
  const float4 a = *(const float4*)g;
  const float4 b = *(const float4*)(g + 4);
  ushort4 lo, hi;
  lo.x = f2bf(a.x); lo.y = f2bf(a.y); lo.z = f2bf(a.z); lo.w = f2bf(a.w);
  hi.x = f2bf(b.x); hi.y = f2bf(b.y); hi.z = f2bf(b.z); hi.w = f2bf(b.w);
  *(ushort4*)s = lo;
  *(ushort4*)(s + 4) = hi;
}

// fp32 -> bf16 for up to 7 tensors in one launch.
struct CvtArgs {
  const float* src[7];
  u16* dst[7];
};
__global__ __launch_bounds__(256) void cvt7(CvtArgs args, int yoff, int nact) {
  const int y = blockIdx.y + yoff;
  const int i = (blockIdx.x * 256 + threadIdx.x) * 8;
  if (y < 3) {
    if (i < nact) stage8f(args.src[y] + i, args.dst[y] + i);
  } else {
    if (i < 4 * (1 << 20)) {
      const int j = i >> 20, off = i & ((1 << 20) - 1);
      stage8f(args.src[3 + j] + off, args.dst[3 + j] + off);
    }
  }
}

// 128x128x(BK=32) MFMA GEMM core (m97 structure), XOR-swizzled LDS.
template<bool ADMA, bool BDMA>
__device__ __forceinline__ void gemm_core(
    const void* __restrict__ Av, const void* __restrict__ Wv,
    int tid, int m0, int n0, u16* As, u16* Bs, f32x4 (&acc)[4][4])
{
  const int srow = tid >> 2, cslot = tid & 3;
  const int gc = cslot ^ ((srow >> 1) & 3);   // swizzled global chunk
  const int w = tid >> 6, l = tid & 63;
  const int quad = l >> 4, l15 = l & 15;
  const int sw = (l15 >> 1) & 3;
  const int wm = (w & 1) << 6, wn = (w >> 1) << 6;

  for (int k0 = 0; k0 < HID; k0 += 32) {
    if (ADMA) {
      const u16* ag = (const u16*)Av + (size_t)(m0 + srow) * HID + k0 + gc * 8;
      lds16(ag, &As[tid * 8]);
      lds16(ag + (size_t)64 * HID, &As[2048 + tid * 8]);
    } else {
      const float* ag = (const float*)Av + (size_t)(m0 + srow) * HID + k0 + gc * 8;
      stage8f(ag, &As[srow * 32 + cslot * 8]);
      stage8f(ag + (size_t)64 * HID, &As[(64 + srow) * 32 + cslot * 8]);
    }
    if (BDMA) {
      const u16* bg = (const u16*)Wv + (size_t)(n0 + srow) * HID + k0 + gc * 8;
      lds16(bg, &Bs[tid * 8]);
      lds16(bg + (size_t)64 * HID, &Bs[2048 + tid * 8]);
    } else {
      const float* bg = (const float*)Wv + (size_t)(n0 + srow) * HID + k0 + gc * 8;
      stage8f(bg, &Bs[srow * 32 + cslot * 8]);
      stage8f(bg + (size_t)64 * HID, &Bs[(64 + srow) * 32 + cslot * 8]);
    }
    __syncthreads();

    bf16x8 a[4], b[4];
    #pragma unroll
    for (int i = 0; i < 4; ++i)
      a[i] = *(const bf16x8*)&As[(wm + i * 16 + l15) * 32 + (quad ^ sw) * 8];
    #pragma unroll
    for (int j = 0; j < 4; ++j)
      b[j] = *(const bf16x8*)&Bs[(wn + j * 16 + l15) * 32 + (quad ^ sw) * 8];
    #pragma unroll
    for (int i = 0; i < 4; ++i)
      #pragma unroll
      for (int j = 0; j < 4; ++j)
        acc[i][j] = MFMA16(a[i], b[j], acc[i][j]);
    __syncthreads();
  }
}

// Fused QKV projection (blockIdx.z selects q/k/v); epilogues as before:
// Q *QSCALE*mask, K plain [bh][s][64], V [bh][d][s] key-permuted per 64-group.
template<bool ADMA, bool BDMA>
__global__ __launch_bounds__(256) void gemm_qkv(
    const void* __restrict__ xq, const void* __restrict__ xk,
    const void* __restrict__ xv,
    const void* __restrict__ wqv, const void* __restrict__ wkv,
    const void* __restrict__ wvv,
    const float* __restrict__ bq, const float* __restrict__ bk,
    const float* __restrict__ bv, const int* __restrict__ Mask,
    u16* __restrict__ qh, u16* __restrict__ kh, u16* __restrict__ vt)
{
  __shared__ u16 As[128 * 32];
  __shared__ u16 Bs[128 * 32];
  const int z = blockIdx.z;
  const void* A = (z == 0) ? xq : (z == 1) ? xk : xv;
  const void* W = (z == 0) ? wqv : (z == 1) ? wkv : wvv;
  const float* Bias = (z == 0) ? bq : (z == 1) ? bk : bv;

  const int tid = threadIdx.x;
  const int m0 = blockIdx.x << 7, n0 = blockIdx.y << 7;
  f32x4 acc[4][4] = {};
  gemm_core<ADMA, BDMA>(A, W, tid, m0, n0, As, Bs, acc);

  const int w = tid >> 6, l = tid & 63;
  const int quad = l >> 4, l15 = l & 15;
  const int wm = (w & 1) << 6, wn = (w >> 1) << 6;

  if (z <= 1) {
    u16* Out = (z == 0) ? qh : kh;
    #pragma unroll
    for (int i = 0; i < 4; ++i) {
      float fl[4];
      #pragma unroll
      for (int r = 0; r < 4; ++r) {
        const int m = m0 + wm + i * 16 + (quad << 2) + r;
        fl[r] = (z == 0) ? (Mask[m] ? QSCALE : 0.f) : 1.f;
      }
      #pragma unroll
      for (int j = 0; j < 4; ++j) {
        const int n = n0 + wn + j * 16 + l15;
        const float bias = Bias[n];
        const int h = n >> 6, d = n & 63;
        #pragma unroll
        for (int r = 0; r < 4; ++r) {
          const int m = m0 + wm + i * 16 + (quad << 2) + r;
          const int bb = m >> 11, s = m & (SEQ - 1);
          Out[((size_t)(bb * HEADS + h) * SEQ + s) * DHEAD + d] =
              f2bf((acc[i][j][r] + bias) * fl[r]);
        }
      }
    }
  } else {
    const int sblk = (m0 + wm) & (SEQ - 1);
    const int bb = (m0 + wm) >> 11;
    #pragma unroll
    for (int j = 0; j < 4; ++j) {
      const int n = n0 + wn + j * 16 + l15;
      const float bias = Bias[n];
      const int h = n >> 6, d = n & 63;
      u16* base = vt + ((size_t)(bb * HEADS + h) * DHEAD + d) * SEQ + sblk;
      #pragma unroll
      for (int r = 0; r < 4; ++r) {
        ushort4 pk;
        pk.x = f2bf(acc[0][j][r] + bias);
        pk.y = f2bf(acc[1][j][r] + bias);
        pk.z = f2bf(acc[2][j][r] + bias);
        pk.w = f2bf(acc[3][j][r] + bias);
        *(ushort4*)(base + ((quad << 2) + r) * 4) = pk;
      }
    }
  }
}

// Output projection: fp32 out = hidden(bf16) @ wo^T + bo
template<bool BDMA>
__global__ __launch_bounds__(256) void gemm_out(
    const u16* __restrict__ hidden, const void* __restrict__ wov,
    const float* __restrict__ bo, float* __restrict__ Out)
{
  __shared__ u16 As[128 * 32];
  __shared__ u16 Bs[128 * 32];
  const int tid = threadIdx.x;
  const int m0 = blockIdx.x << 7, n0 = blockIdx.y << 7;
  f32x4 acc[4][4] = {};
  gemm_core<true, BDMA>(hidden, wov, tid, m0, n0, As, Bs, acc);

  const int w = tid >> 6, l = tid & 63;
  const int quad = l >> 4, l15 = l & 15;
  const int wm = (w & 1) << 6, wn = (w >> 1) << 6;
  #pragma unroll
  for (int j = 0; j < 4; ++j) {
    const int n = n0 + wn + j * 16 + l15;
    const float bias = bo[n];
    #pragma unroll
    for (int i = 0; i < 4; ++i) {
      const int mb = m0 + wm + i * 16 + (quad << 2);
      #pragma unroll
      for (int r = 0; r < 4; ++r)
        Out[(size_t)(mb + r) * HID + n] = acc[i][j][r] + bias;
    }
  }
}

// Flash attention, no-max softmax, split-K capable.
// 256 threads = 4 waves; wave w owns queries q0+w*64..+63 (block = 256 q).
// MODE 0: full SEQ keys, normalize in-kernel -> Hidden.
// MODE 1/2: half the keys (z = lin>>9); raw o + matched lsum partials to ws
//           (1 = bf16 partials, 2 = fp32); combine kernel normalizes.
// LDS 48 KB: QP 32 KB (Q staging, then P wave-private [w][64q][64k] XOR-
// swizzled) + Ks 8 KB + Vt 8 KB -> 3 blocks/CU = 12 waves (vs 8 in r6).
// P stored by TRUNCATION; lsum accumulates the truncated values -> the
// softmax normalization is exact over the weights actually used.
template<int MODE>
__global__ __launch_bounds__(256, 3) void attn_mfma(
    const u16* __restrict__ QH, const u16* __restrict__ KH,
    const u16* __restrict__ VT, u16* __restrict__ Hidden,
    void* __restrict__ OPart, float* __restrict__ LSum)
{
  __shared__ u16 QP[256 * 64];     // 32 KB
  __shared__ u16 Ks[2][64 * 32];   // 8 KB
  __shared__ u16 Vt[2][64 * 32];   // 8 KB

  const int tid = threadIdx.x;     // 0..255
  const int w = tid >> 6, l = tid & 63;
  const int quad = l >> 4, l15 = l & 15;
  const int sw = (l15 >> 1) & 3;
  const int srow = tid >> 2, cslot = tid & 3;
  const int gc = cslot ^ ((srow >> 1) & 3);

  const int lin = blockIdx.x;
  const int bh = lin & 63, b = bh >> 4, h = bh & 15;  // XCD remap
  const int qt = (lin >> 6) & 7;
  const int z  = (MODE == 0) ? 0 : (lin >> 9);
  const int q0 = qt << 8;
  const int nk = (MODE == 0) ? SEQ : SEQ / 2;
  const int tb = z * (SEQ / 2);

  const u16* qbase = QH + (size_t)bh * SEQ * DHEAD;
  const u16* kbase = KH + (size_t)bh * SEQ * DHEAD;
  const u16* vbase = VT + (size_t)bh * DHEAD * SEQ;

  // stage Q (256 rows x 64 B), layout [hh][row][32]
  #pragma unroll
  for (int hh = 0; hh < 2; ++hh)
    #pragma unroll
    for (int part = 0; part < 4; ++part)
      lds16(qbase + (size_t)(q0 + part * 64 + srow) * DHEAD + hh * 32 + gc * 8,
            &QP[hh * 8192 + part * 2048 + tid * 8]);
  __syncthreads();  // drains vmcnt

  bf16x8 aq[2][4];
  #pragma unroll
  for (int hh = 0; hh < 2; ++hh)
    #pragma unroll
    for (int i = 0; i < 4; ++i)
      aq[hh][i] = *(const bf16x8*)
          &QP[hh * 8192 + (w * 64 + i * 16 + l15) * 32 + (quad ^ sw) * 8];

  float lsum[4][4] = {};
  f32x4 o[4][4] = {};

  for (int t = 0; t < nk; t += 64) {
    const int t0 = tb + t;
    __syncthreads();  // prior-iter LDS reads (and init aq reads) done
    #pragma unroll
    for (int hh = 0; hh < 2; ++hh) {
      lds16(kbase + (size_t)(t0 + srow) * DHEAD + hh * 32 + gc * 8, &Ks[hh][tid * 8]);
      lds16(vbase + (size_t)srow * SEQ + t0 + hh * 32 + gc * 8, &Vt[hh][tid * 8]);
    }
    __syncthreads();  // staging visible

    // S = Q K^T (log2-domain)
    f32x4 s[4][4] = {};
    #pragma unroll
    for (int j = 0; j < 4; ++j)
      #pragma unroll
      for (int hh = 0; hh < 2; ++hh) {
        const bf16x8 bk = *(const bf16x8*)
            &Ks[hh][(j * 16 + l15) * 32 + (quad ^ sw) * 8];
        #pragma unroll
        for (int i = 0; i < 4; ++i)
          s[i][j] = MFMA16(aq[hh][i], bk, s[i][j]);
      }

    // P = exp2(S), truncate to bf16, lsum over truncated values.
    // wave-private P region w*4096; row stride 64 u16; chunk XOR swizzle.
    #pragma unroll
    for (int i = 0; i < 4; ++i)
      #pragma unroll
      for (int r = 0; r < 4; ++r) {
        const u32 u0 = fbits(EXP2F(s[i][0][r]));
        const u32 u1 = fbits(EXP2F(s[i][1][r]));
        const u32 u2 = fbits(EXP2F(s[i][2][r]));
        const u32 u3 = fbits(EXP2F(s[i][3][r]));
        lsum[i][r] += (asf(u0 & 0xffff0000u) + asf(u1 & 0xffff0000u)) +
                      (asf(u2 & 0xffff0000u) + asf(u3 & 0xffff0000u));
        const u32 lo = (u0 >> 16) | (u1 & 0xffff0000u);
        const u32 hi = (u2 >> 16) | (u3 & 0xffff0000u);
        const int row = i * 16 + (quad << 2) + r;
        const int cs = ((l15 >> 1) ^ (row & 7)) * 8 + (l15 & 1) * 4;
        uint2 pk; pk.x = lo; pk.y = hi;
        *(uint2*)&QP[w * 4096 + row * 64 + cs] = pk;
      }
    // P rows wave-private: intra-wave LDS write->read ordering enforced.

    // O += P V  (keys permuted consistently in P and Vt)
    #pragma unroll
    for (int hh = 0; hh < 2; ++hh) {
      bf16x8 ap[4];
      #pragma unroll
      for (int i = 0; i < 4; ++i)
        ap[i] = *(const bf16x8*)
            &QP[w * 4096 + (i * 16 + l15) * 64 + (((hh * 4 + quad) ^ (l15 & 7)) << 3)];
      #pragma unroll
      for (int j = 0; j < 4; ++j) {
        const bf16x8 vb = *(const bf16x8*)
            &Vt[hh][(j * 16 + l15) * 32 + (quad ^ sw) * 8];
        #pragma unroll
        for (int i = 0; i < 4; ++i)
          o[i][j] = MFMA16(ap[i], vb, o[i][j]);
      }
    }
  }

  // reduce lsum across the 16-lane group
  #pragma unroll
  for (int i = 0; i < 4; ++i)
    #pragma unroll
    for (int r = 0; r < 4; ++r) {
      float t = lsum[i][r];
      #pragma unroll
      for (int off = 1; off < 16; off <<= 1)
        t += __shfl_xor(t, off);
      lsum[i][r] = t;
    }

  if (MODE == 0) {
    #pragma unroll
    for (int i = 0; i < 4; ++i)
      #pragma unroll
      for (int j = 0; j < 4; ++j)
        #pragma unroll
        for (int r = 0; r < 4; ++r) {
          const int qrow = q0 + w * 64 + i * 16 + (quad << 2) + r;
          Hidden[((size_t)(b * SEQ + qrow)) * HID + h * DHEAD + j * 16 + l15] =
              f2bf(o[i][j][r] / lsum[i][r]);
        }
  } else {
    // raw partials: o -> OPart[z][bh][s][64], lsum -> LSum[z][bh][s]
    const size_t obase = (size_t)z * (SEQ * (size_t)64 * DHEAD)
                       + (size_t)bh * SEQ * DHEAD;
    #pragma unroll
    for (int i = 0; i < 4; ++i)
      #pragma unroll
      for (int j = 0; j < 4; ++j)
        #pragma unroll
        for (int r = 0; r < 4; ++r) {
          const int s0 = q0 + w * 64 + i * 16 + (quad << 2) + r;
          const size_t idx = obase + (size_t)s0 * DHEAD + j * 16 + l15;
          if (MODE == 2) ((float*)OPart)[idx] = o[i][j][r];
          else           ((u16*)OPart)[idx]   = f2bf(o[i][j][r]);
        }
    if (l15 == 0) {
      #pragma unroll
      for (int i = 0; i < 4; ++i)
        #pragma unroll
        for (int r = 0; r < 4; ++r) {
          const int s0 = q0 + w * 64 + i * 16 + (quad << 2) + r;
          LSum[z * (64 * SEQ) + bh * SEQ + s0] = lsum[i][r];
        }
    }
  }
}

// combine: hidden = (o0 + o1) / (l0 + l1), bf16 out.  8 elems/thread.
template<int MODE>
__global__ __launch_bounds__(256) void combine(
    const void* __restrict__ OPart, const float* __restrict__ LSum,
    u16* __restrict__ Hidden)
{
  const int g = (blockIdx.x * 256 + threadIdx.x) * 8;
  const int d = g & 63;
  const int rest = g >> 6;            // bh*SEQ + s
  const int bh = rest >> 11, s = rest & (SEQ - 1);
  const int b = bh >> 4, h = bh & 15;
  const float inv = 1.f / (LSum[rest] + LSum[64 * SEQ + rest]);
  const size_t half = (size_t)64 * SEQ * DHEAD;

  float v[8];
  if (MODE == 2) {
    const float* o = (const float*)OPart;
    #pragma unroll
    for (int t = 0; t < 8; ++t) v[t] = o[g + t] + o[half + g + t];
  } else {
    const u16* o = (const u16*)OPart;
    const uint4 a = *(const uint4*)(o + g);
    const uint4 c = *(const uint4*)(o + half + g);
    v[0] = bflo(a.x) + bflo(c.x); v[1] = bfhi(a.x) + bfhi(c.x);
    v[2] = bflo(a.y) + bflo(c.y); v[3] = bfhi(a.y) + bfhi(c.y);
    v[4] = bflo(a.z) + bflo(c.z); v[5] = bfhi(a.z) + bfhi(c.z);
    v[6] = bflo(a.w) + bflo(c.w); v[7] = bfhi(a.w) + bfhi(c.w);
  }
  ushort4 p0, p1;
  p0.x = f2bf(v[0] * inv); p0.y = f2bf(v[1] * inv);
  p0.z = f2bf(v[2] * inv); p0.w = f2bf(v[3] * inv);
  p1.x = f2bf(v[4] * inv); p1.y = f2bf(v[5] * inv);
  p1.z = f2bf(v[6] * inv); p1.w = f2bf(v[7] * inv);
  u16* out = Hidden + ((size_t)(b * SEQ + s)) * HID + h * DHEAD + d;
  *(ushort4*)out = p0;
  *(ushort4*)(out + 4) = p1;
}

extern "C" void kernel_launch(void* const* d_in, const int* in_sizes, int n_in,
                              void* d_out, int out_size, void* d_ws, size_t ws_size,
                              hipStream_t stream) {
  const float* q  = (const float*)d_in[0];
  const float* k  = (const float*)d_in[1];
  const float* v  = (const float*)d_in[2];
  const int* mask = (const int*)d_in[3];
  const float* wq = (const float*)d_in[4];
  const float* bq = (const float*)d_in[5];
  const float* wk = (const float*)d_in[6];
  const float* bk = (const float*)d_in[7];
  const float* wv = (const float*)d_in[8];
  const float* bv = (const float*)d_in[9];
  const float* wo = (const float*)d_in[10];
  const float* bo = (const float*)d_in[11];

  const size_t SEG = (size_t)MROWS * HID;   // 8388608
  const size_t WSEG = (size_t)HID * HID;    // 1<<20
  const dim3 gq(MROWS / 128, HID / 128, 3);
  const dim3 go(MROWS / 128, HID / 128);

  const size_t FULLB    = (6 * SEG + 4 * WSEG) * sizeof(u16);        // ~109 MB
  const size_t LSUMB    = 2 * 64 * SEQ * sizeof(float);              // 1 MB
  const size_t SPLIT32B = FULLB + 2 * SEG * sizeof(float) + LSUMB;   // ~177 MB
  const size_t SPLIT16B = FULLB + 2 * SEG * sizeof(u16) + LSUMB;     // ~144 MB

  if (ws_size >= FULLB) {
    u16* qb  = (u16*)d_ws;
    u16* kb  = qb + SEG;
    u16* vb  = kb + SEG;
    u16* qh  = vb + SEG;
    u16* kh  = qh + SEG;
    u16* vt  = kh + SEG;
    u16* wqb = vt + SEG;
    u16* wkb = wqb + WSEG;
    u16* wvb = wkb + WSEG;
    u16* wob = wvb + WSEG;
    u16* hidden = qb;  // alias (qb dead after gemm_qkv)
    void* opart = (void*)(wob + WSEG);
    float* lsum32 = (float*)((char*)opart +
        ((ws_size >= SPLIT32B) ? 2 * SEG * sizeof(float) : 2 * SEG * sizeof(u16)));

    CvtArgs ca;
    ca.src[0] = q;  ca.dst[0] = qb;
    ca.src[1] = k;  ca.dst[1] = kb;
    ca.src[2] = v;  ca.dst[2] = vb;
    ca.src[3] = wq; ca.dst[3] = wqb;
    ca.src[4] = wk; ca.dst[4] = wkb;
    ca.src[5] = wv; ca.dst[5] = wvb;
    ca.src[6] = wo; ca.dst[6] = wob;
    cvt7<<<dim3(SEG / 2048, 4), 256, 0, stream>>>(ca, 0, (int)SEG);

    gemm_qkv<true, true><<<gq, 256, 0, stream>>>(qb, kb, vb, wqb, wkb, wvb,
                                                 bq, bk, bv, mask, qh, kh, vt);
    if (ws_size >= SPLIT32B) {
      attn_mfma<2><<<1024, 256, 0, stream>>>(qh, kh, vt, hidden, opart, lsum32);
      combine<2><<<SEG / 2048, 256, 0, stream>>>(opart, lsum32, hidden);
    } else if (ws_size >= SPLIT16B) {
      attn_mfma<1><<<1024, 256, 0, stream>>>(qh, kh, vt, hidden, opart, lsum32);
      combine<1><<<SEG / 2048, 256, 0, stream>>>(opart, lsum32, hidden);
    } else {
      attn_mfma<0><<<512, 256, 0, stream>>>(qh, kh, vt, hidden, nullptr, nullptr);
    }
    gemm_out<true><<<go, 256, 0, stream>>>(hidden, wob, bo, (float*)d_out);
  } else {
    // MID/LOW fallback: weights bf16 if they fit, activations VALU-staged.
    const size_t MIDB = (4 * SEG + 4 * WSEG) * sizeof(u16);
    if (ws_size >= MIDB) {
      u16* wqb = (u16*)d_ws;
      u16* wkb = wqb + WSEG;
      u16* wvb = wkb + WSEG;
      u16* wob = wvb + WSEG;
      u16* qh = wob + WSEG;
      u16* kh = qh + SEG;
      u16* vt = kh + SEG;
      u16* hidden = vt + SEG;

      CvtArgs ca;
      ca.src[0] = ca.src[1] = ca.src[2] = q;
      ca.dst[0] = ca.dst[1] = ca.dst[2] = wqb;
      ca.src[3] = wq; ca.dst[3] = wqb;
      ca.src[4] = wk; ca.dst[4] = wkb;
      ca.src[5] = wv; ca.dst[5] = wvb;
      ca.src[6] = wo; ca.dst[6] = wob;
      cvt7<<<dim3(4 * WSEG / 2048, 1), 256, 0, stream>>>(ca, 3, 0);

      gemm_qkv<false, true><<<gq, 256, 0, stream>>>(q, k, v, wqb, wkb, wvb,
                                                    bq, bk, bv, mask, qh, kh, vt);
      attn_mfma<0><<<512, 256, 0, stream>>>(qh, kh, vt, hidden, nullptr, nullptr);
      gemm_out<true><<<go, 256, 0, stream>>>(hidden, wob, bo, (float*)d_out);
    } else {
      u16* qh = (u16*)d_ws;
      u16* kh = qh + SEG;
      u16* vt = kh + SEG;
      u16* hidden = vt + SEG;
      gemm_qkv<false, false><<<gq, 256, 0, stream>>>(q, k, v, wq, wk, wv,
                                                     bq, bk, bv, mask, qh, kh, vt);
      attn_mfma<0><<<512, 256, 0, stream>>>(qh, kh, vt, hidden, nullptr, nullptr);
      gemm_out<false><<<go, 256, 0, stream>>>(hidden, wo, bo, (float*)d_out);
    }
  }
}